// Round 6
// baseline (338.559 us; speedup 1.0000x reference)
//
#include <hip/hip_runtime.h>
#include <math.h>

// ---------------------------------------------------------------------------
// TemporalSSMPatchwise: b=8,t=15,H=480,W=640, PS=8 -> hp=60,wp=80, n=4800
// d=64, P=32, pp=64.  N_seq = 38400.
// Transpose-free dataflow: weights are MFMA A-operands (pre-permuted rows),
// activations are B-operands.  chan(nt,qd,r) = (nt>>1)*32+qd*8+(nt&1)*4+r;
// D-output register layout of one matmul IS the B-operand layout of the next.
// MFMA 16x16x32 bf16: A[m=lane&15][k=qd*8+j], B[k=qd*8+j][n=lane&15],
// D: col=lane&15, row=qd*4+reg (m89/m91-verified).
//
// v6: DENSE-RUN staging.  v3..v5 all ingested x as scattered 512B runs and
// all plateaued at ~2 TB/s effective (BW_eff roofline, invariant to barriers
// and privacy).  Re-tile: block = 80 patches = one full patch-row (5 waves
// x 16 seqs, grid 480x320).  Its per-t x footprint = 8 CONSECUTIVE image
// rows x 2560B = ONE contiguous 20KB span -> staging is identity-mapped,
// 20 x global_load_lds(1KB) forming a single dense 20KB stream.  Cross-wave
// row sharing -> 2-barrier coop loop (v4==v5 showed barriers are free).
// LDS: 16KB weights + 2x20KB dbuf = 56KB -> 2 blocks/CU.  Scan math, head,
// fused W_out epilogue unchanged.
// ---------------------------------------------------------------------------

typedef __attribute__((ext_vector_type(8))) short short8;
typedef __attribute__((ext_vector_type(4))) float f32x4;

#define MFMA16(a, b, c) __builtin_amdgcn_mfma_f32_16x16x32_bf16((a), (b), (c), 0, 0, 0)

__device__ __forceinline__ short f2bf(float f) {
  union { float f; unsigned u; } v; v.f = f;
  unsigned r = (v.u + 0x7fffu + ((v.u >> 16) & 1u)) >> 16;  // RNE
  return (short)r;
}
__device__ __forceinline__ float geluf(float x) {
  return 0.5f * x * (1.0f + erff(x * 0.70710678118654752f));
}
// pack two C-layout f32x4 tiles (2kt, 2kt+1) into one bf16 B-operand frag
__device__ __forceinline__ short8 packfrag(const f32x4& a, const f32x4& b) {
  short8 o;
  o[0] = f2bf(a[0]); o[1] = f2bf(a[1]); o[2] = f2bf(a[2]); o[3] = f2bf(a[3]);
  o[4] = f2bf(b[0]); o[5] = f2bf(b[1]); o[6] = f2bf(b[2]); o[7] = f2bf(b[3]);
  return o;
}
// weight-row permutation: A-row a = i*16+m  ->  actual channel
__device__ __forceinline__ int ecmap(int i, int m) {
  return (i >> 1) * 32 + (m >> 2) * 8 + (i & 1) * 4 + (m & 3);
}
__device__ __forceinline__ void bbar_factors(const float* Lre, const float* Lim,
                                             const float* lstep, int p,
                                             float& fre, float& fim) {
  float st = expf(lstep[p]);
  float lr = Lre[p], li = Lim[p];
  float er = expf(lr * st);
  float lbr = er * cosf(li * st), lbi = er * sinf(li * st);
  float u = lbr - 1.0f, v = lbi;
  float den = lr * lr + li * li;
  fre = (u * lr + v * li) / den;
  fim = (v * lr - u * li) / den;
}

// ---------------------------------------------------------------------------
// K0: pack 176 A-operand fragments (1 KB each) + bu0.
// ids: 0..7 W_embed | 8..15 Bbar'(g1-folded) | 16..23 Cc2(mask-folded)
//      24..39 W_enc | 40..47 W_dec | 48..175 W_out (natural rows)
// frag(i,kt) value[j] at lane(qd,m): A[i*16+m][k=kt*32+qd*8+j]
// ---------------------------------------------------------------------------
__global__ __launch_bounds__(256) void k0_prep(
    const float* __restrict__ W_embed, const float* __restrict__ g1,
    const float* __restrict__ be1, const float* __restrict__ Lre,
    const float* __restrict__ Lim, const float* __restrict__ Bre,
    const float* __restrict__ Bim, const float* __restrict__ Cre,
    const float* __restrict__ Cim, const float* __restrict__ lstep,
    const float* __restrict__ W_enc, const float* __restrict__ W_dec,
    const float* __restrict__ W_out, short* __restrict__ wimg,
    float* __restrict__ bu0) {
  const int bid = blockIdx.x;
  if (bid == 44) {  // bu0[q] = sum_d beta1[d] * Bbar_comp[p][d]
    int q = threadIdx.x;
    if (q < 64) {
      int c = q >> 5, p = q & 31;
      float fre, fim; bbar_factors(Lre, Lim, lstep, p, fre, fim);
      float s = 0.f;
      for (int d = 0; d < 64; ++d) {
        float br = Bre[p * 64 + d], bi = Bim[p * 64 + d];
        float val = c ? (fre * bi + fim * br) : (fre * br - fim * bi);
        s += be1[d] * val;
      }
      bu0[q] = s;
    }
    return;
  }
  const int w = threadIdx.x >> 6, lane = threadIdx.x & 63;
  const int m = lane & 15, qd = lane >> 4;
  const int f = bid * 4 + w;
  short v[8];
  if (f < 8) {
    int i = f >> 1, kt = f & 1, chan = ecmap(i, m), k0 = kt * 32 + qd * 8;
#pragma unroll
    for (int j = 0; j < 8; ++j) v[j] = f2bf(W_embed[chan * 64 + k0 + j]);
  } else if (f < 16) {
    int fi = f - 8, i = fi >> 1, kt = fi & 1;
    int comp = i & 1, p = (i >> 1) * 16 + m, d0 = kt * 32 + qd * 8;
    float fre, fim; bbar_factors(Lre, Lim, lstep, p, fre, fim);
#pragma unroll
    for (int j = 0; j < 8; ++j) {
      int d = d0 + j;
      float br = Bre[p * 64 + d], bi = Bim[p * 64 + d];
      float val = comp ? (fre * bi + fim * br) : (fre * br - fim * bi);
      v[j] = f2bf(g1[d] * val);
    }
  } else if (f < 24) {
    int fi = f - 16, i = fi >> 1, kt = fi & 1, chan = ecmap(i, m);
#pragma unroll
    for (int j = 0; j < 8; ++j) {
      int comp = j >> 2, p = kt * 16 + qd * 4 + (j & 3);
      float stp = expf(lstep[p]);
      float fr = stp * fabsf(Lim[p]) * (1.0f / 6.28318530717958648f);
      float msk = (fr < 0.5f) ? 1.f : 0.f;
      float val = comp ? -Cim[chan * 32 + p] * msk : Cre[chan * 32 + p] * msk;
      v[j] = f2bf(val);
    }
  } else if (f < 40) {
    int fi = f - 24, i = fi >> 1, kt = fi & 1;
    int row = (i < 4) ? ecmap(i, m) : 64 + ecmap(i - 4, m);
#pragma unroll
    for (int j = 0; j < 8; ++j) v[j] = f2bf(W_enc[row * 64 + kt * 32 + qd * 8 + j]);
  } else if (f < 48) {
    int fi = f - 40, i = fi >> 1, kt = fi & 1, row = ecmap(i, m);
#pragma unroll
    for (int j = 0; j < 8; ++j) v[j] = f2bf(W_dec[row * 64 + kt * 32 + qd * 8 + j]);
  } else {
    int fi = f - 48, i = fi >> 1, kt = fi & 1, row = i * 16 + m;  // natural
#pragma unroll
    for (int j = 0; j < 8; ++j) v[j] = f2bf(W_out[row * 64 + kt * 32 + qd * 8 + j]);
  }
  short8 sv;
#pragma unroll
  for (int j = 0; j < 8; ++j) sv[j] = v[j];
  *(short8*)&wimg[(f * 64 + lane) * 8] = sv;
}

// ---------------------------------------------------------------------------
// K1: embed -> LN1 -> Bu -> scan -> head(MLP) -> LN3 -> W_out -> y.
// 320 thr = 5 waves x 16 seqs = 80 patches = one full patch-row; grid 480.
// LDS: [0,16K) scan frags, [16K,16K+40960) 2x20KB dense-tile dbuf (head
// frags swapped into [16K,48K) after the scan).  56KB -> 2 blocks/CU.
// ---------------------------------------------------------------------------
__global__ __launch_bounds__(320) void k1_fused(
    const float* __restrict__ x, const short* __restrict__ wimg_g,
    const float* __restrict__ bu0_g, const float* __restrict__ Lre,
    const float* __restrict__ Lim, const float* __restrict__ lstep,
    const float* __restrict__ g1, const float* __restrict__ be1,
    const float* __restrict__ bemb, const float* __restrict__ Dv,
    const float* __restrict__ g2, const float* __restrict__ be2,
    const float* __restrict__ g3, const float* __restrict__ be3,
    const float* __restrict__ b_out, float* __restrict__ y) {
  __shared__ __align__(16) char smem[57344];
#define WF(id) (*(const short8*)(smem + (id) * 1024 + lane * 16))

  const int tid = threadIdx.x;
  const int wv = tid >> 6, lane = tid & 63;
  const int s = lane & 15, qd = lane >> 4;

  // ---- per-lane constants ----
  int cb[4];
  f32x4 bec[4], bu0c[4];
#pragma unroll
  for (int nt = 0; nt < 4; ++nt) {
    cb[nt] = (nt >> 1) * 32 + qd * 8 + (nt & 1) * 4;
    bec[nt] = *(const f32x4*)(bemb + cb[nt]);
    bu0c[nt] = *(const f32x4*)(bu0_g + (nt & 1) * 32 + (nt >> 1) * 16 + qd * 4);
  }
  f32x4 lbr[2], lbi[2];
#pragma unroll
  for (int k = 0; k < 2; ++k)
#pragma unroll
    for (int r = 0; r < 4; ++r) {
      int p = k * 16 + qd * 4 + r;
      float st = expf(lstep[p]);
      float er = expf(Lre[p] * st);
      lbr[k][r] = er * cosf(Lim[p] * st);
      lbi[k][r] = er * sinf(Lim[p] * st);
    }

  // ---- geometry ----
  // Block = patch-row ph of batch b_i: 80 patches, 8 consecutive image rows.
  // Per-t tile = 20480B CONTIGUOUS in x (rows ph*8..ph*8+7).  LDS = identity.
  const int b_i = blockIdx.x / 60;
  const int ph = blockIdx.x % 60;
  const int tb0 = ((b_i * 15) * 480 + ph * 8) * 640;  // float offset of tile, t=0
  const int sbase = blockIdx.x * 80 + wv * 16;
  // fragment read byte offsets within a tile: row kt*4+qd, patch wv*16+s, half h
  int rb[4];
#pragma unroll
  for (int kt = 0; kt < 2; ++kt)
#pragma unroll
    for (int h = 0; h < 2; ++h)
      rb[kt * 2 + h] = (kt * 4 + qd) * 2560 + (wv * 16 + s) * 32 + h * 16;

#define STAGE(bufofs, tt)                                                     \
  {                                                                           \
    const float* gsrc = x + tb0 + (tt) * 307200 + wv * 1024;                  \
    char* lb = smem + (bufofs) + wv * 4096;                                   \
    _Pragma("unroll") for (int j = 0; j < 4; ++j)                             \
        __builtin_amdgcn_global_load_lds(                                     \
            (const __attribute__((address_space(1))) void*)(gsrc + j * 256 +  \
                                                            lane * 4),        \
            (__attribute__((address_space(3))) void*)(lb + j * 1024),         \
            16, 0, 0);                                                        \
  }

  // ---- prologue: stage t=0,t=1 (async), weights -> LDS, full drain ----
  STAGE(16384, 0);
  STAGE(36864, 1);
  {
    float4* wdst = (float4*)smem;
    const float4* wsrc = (const float4*)wimg_g;
    for (int i = tid; i < 1024; i += 320) wdst[i] = wsrc[i];
  }
  asm volatile("s_waitcnt vmcnt(0) lgkmcnt(0)" ::: "memory");
  __builtin_amdgcn_s_barrier();

  const f32x4 zf = {0.f, 0.f, 0.f, 0.f};
  f32x4 state[4] = {zf, zf, zf, zf};
  f32x4 xh[4];

  for (int t = 0; t < 15; ++t) {
    // read this tile's fragments from buf[t&1]
    const char* bufr = smem + 16384 + (t & 1) * 20480;
    f32x4 vcur[4];
#pragma unroll
    for (int q = 0; q < 4; ++q) vcur[q] = *(const f32x4*)(bufr + rb[q]);
    asm volatile("s_waitcnt lgkmcnt(0)" ::: "memory");  // reads retired
    __builtin_amdgcn_s_barrier();  // B1: all waves done reading buf[t&1]
    if (t < 13) STAGE(16384 + (t & 1) * 20480, t + 2);  // overwrite, async

    short8 pa0 = packfrag(vcur[0], vcur[1]);
    short8 pa1 = packfrag(vcur[2], vcur[3]);
    f32x4 c1[4];
#pragma unroll
    for (int i = 0; i < 4; ++i) {
      f32x4 acc = MFMA16(WF(i * 2), pa0, zf);
      acc = MFMA16(WF(i * 2 + 1), pa1, acc);
      c1[i] = acc + bec[i];
    }
    float sm = 0.f, sq = 0.f;
#pragma unroll
    for (int nt = 0; nt < 4; ++nt)
#pragma unroll
      for (int i = 0; i < 4; ++i) { sm += c1[nt][i]; sq += c1[nt][i] * c1[nt][i]; }
    sm += __shfl_xor(sm, 16); sq += __shfl_xor(sq, 16);
    sm += __shfl_xor(sm, 32); sq += __shfl_xor(sq, 32);
    float mean = sm * 0.015625f;
    float rstd = rsqrtf(sq * 0.015625f - mean * mean + 1e-5f);
#pragma unroll
    for (int nt = 0; nt < 4; ++nt) xh[nt] = (c1[nt] - mean) * rstd;
    short8 xa0 = packfrag(xh[0], xh[1]);
    short8 xa1 = packfrag(xh[2], xh[3]);
#pragma unroll
    for (int k = 0; k < 2; ++k) {
      f32x4 re = state[2 * k], im = state[2 * k + 1];
      state[2 * k]     = lbr[k] * re - lbi[k] * im + bu0c[2 * k];
      state[2 * k + 1] = lbr[k] * im + lbi[k] * re + bu0c[2 * k + 1];
    }
#pragma unroll
    for (int i = 0; i < 4; ++i) {
      state[i] = MFMA16(WF(8 + i * 2), xa0, state[i]);
      state[i] = MFMA16(WF(8 + i * 2 + 1), xa1, state[i]);
    }

    // counted wait: own stage(t+1) done, stage(t+2) stays in flight; then
    // barrier => all waves' stage(t+1) done before iter t+1 reads it.
    if (t < 14) {
      if (t < 13) asm volatile("s_waitcnt vmcnt(4)" ::: "memory");
      else        asm volatile("s_waitcnt vmcnt(0)" ::: "memory");
      __builtin_amdgcn_s_barrier();  // B2
    }
  }
#undef STAGE

  // ---- swap head frags (16..47, 32KB) into the stage-buffer space ----
  __syncthreads();  // all waves done with the dbuf
  {
    float4* dst = (float4*)(smem + 16384);
    const float4* src = (const float4*)(wimg_g + 16 * 512);
    for (int i = tid; i < 2048; i += 320) dst[i] = src[i];
  }
  __syncthreads();

  // ---- head at t = 14 ----
  f32x4 g1c[4], b1c[4], Dc[4], g2c[4], b2c[4];
#pragma unroll
  for (int nt = 0; nt < 4; ++nt) {
    g1c[nt] = *(const f32x4*)(g1 + cb[nt]);
    b1c[nt] = *(const f32x4*)(be1 + cb[nt]);
    Dc[nt] = *(const f32x4*)(Dv + cb[nt]);
    g2c[nt] = *(const f32x4*)(g2 + cb[nt]);
    b2c[nt] = *(const f32x4*)(be2 + cb[nt]);
  }
  f32x4 fxl[4];
#pragma unroll
  for (int nt = 0; nt < 4; ++nt) fxl[nt] = xh[nt] * g1c[nt] + b1c[nt];

  short8 xsa0 = packfrag(state[0], state[1]);
  short8 xsa1 = packfrag(state[2], state[3]);
  f32x4 xbv[4];
#pragma unroll
  for (int i = 0; i < 4; ++i) {
    f32x4 acc = fxl[i] * Dc[i];
    acc = MFMA16(WF(16 + i * 2), xsa0, acc);
    acc = MFMA16(WF(16 + i * 2 + 1), xsa1, acc);
#pragma unroll
    for (int r = 0; r < 4; ++r) xbv[i][r] = geluf(acc[r]) + fxl[i][r];
  }
  float sm2 = 0.f, sq2 = 0.f;
#pragma unroll
  for (int nt = 0; nt < 4; ++nt)
#pragma unroll
    for (int i = 0; i < 4; ++i) { sm2 += xbv[nt][i]; sq2 += xbv[nt][i] * xbv[nt][i]; }
  sm2 += __shfl_xor(sm2, 16); sq2 += __shfl_xor(sq2, 16);
  sm2 += __shfl_xor(sm2, 32); sq2 += __shfl_xor(sq2, 32);
  float mean2 = sm2 * 0.015625f;
  float rstd2 = rsqrtf(sq2 * 0.015625f - mean2 * mean2 + 1e-5f);
  f32x4 fx2[4];
#pragma unroll
  for (int nt = 0; nt < 4; ++nt)
    fx2[nt] = (xbv[nt] - mean2) * rstd2 * g2c[nt] + b2c[nt];

  short8 fa0 = packfrag(fx2[0], fx2[1]);
  short8 fa1 = packfrag(fx2[2], fx2[3]);
  f32x4 e[8];
#pragma unroll
  for (int i = 0; i < 8; ++i) {
    f32x4 acc = MFMA16(WF(24 + i * 2), fa0, zf);
    e[i] = MFMA16(WF(24 + i * 2 + 1), fa1, acc);
  }
  f32x4 hv[4];
#pragma unroll
  for (int nt = 0; nt < 4; ++nt)
#pragma unroll
    for (int i = 0; i < 4; ++i) hv[nt][i] = e[nt][i] * geluf(e[nt + 4][i]);

  short8 ha0 = packfrag(hv[0], hv[1]);
  short8 ha1 = packfrag(hv[2], hv[3]);
  f32x4 xo[4];
#pragma unroll
  for (int i = 0; i < 4; ++i) {
    f32x4 acc = fx2[i];
    acc = MFMA16(WF(40 + i * 2), ha0, acc);
    xo[i] = MFMA16(WF(40 + i * 2 + 1), ha1, acc);
  }

  // ---- fused k2: LN3 + W_out GEMM + pixel-shuffle store ----
  float sm3 = 0.f, sq3 = 0.f;
#pragma unroll
  for (int nt = 0; nt < 4; ++nt)
#pragma unroll
    for (int i = 0; i < 4; ++i) { sm3 += xo[nt][i]; sq3 += xo[nt][i] * xo[nt][i]; }
  sm3 += __shfl_xor(sm3, 16); sq3 += __shfl_xor(sq3, 16);
  sm3 += __shfl_xor(sm3, 32); sq3 += __shfl_xor(sq3, 32);
  float mean3 = sm3 * 0.015625f;
  float rstd3 = rsqrtf(sq3 * 0.015625f - mean3 * mean3 + 1e-5f);
  f32x4 z[4];
#pragma unroll
  for (int nt = 0; nt < 4; ++nt) {
    f32x4 g3c = *(const f32x4*)(g3 + cb[nt]);
    f32x4 b3c = *(const f32x4*)(be3 + cb[nt]);
    z[nt] = (xo[nt] - mean3) * rstd3 * g3c + b3c;
  }
  short8 za = packfrag(z[0], z[1]);
  short8 zb = packfrag(z[2], z[3]);

  const int seq = sbase + s;
  const int bi2 = seq / 4800, prr = seq % 4800;
  const int phh = prr / 80, pww = prr % 80;
  const int obase = (bi2 * 16 * 480 + phh * 8) * 640 + pww * 8;
  const short* wob = wimg_g + 48 * 512;  // W_out frag images (128KB, L2-hot)

#pragma unroll 4
  for (int ntg = 0; ntg < 64; ++ntg) {
    short8 a0 = *(const short8*)&wob[(ntg * 2 + 0) * 512 + lane * 8];
    short8 a1 = *(const short8*)&wob[(ntg * 2 + 1) * 512 + lane * 8];
    int o0 = ntg * 16 + qd * 4;
    f32x4 acc = *(const f32x4*)(b_out + o0);
    acc = MFMA16(a0, za, acc);
    acc = MFMA16(a1, zb, acc);
    int c = o0 >> 6, pi = (o0 >> 3) & 7, pj = o0 & 7;
    *(f32x4*)&y[obase + c * 307200 + pi * 640 + pj] = acc;
  }
#undef WF
}

// ---------------------------------------------------------------------------
extern "C" void kernel_launch(void* const* d_in, const int* in_sizes, int n_in,
                              void* d_out, int out_size, void* d_ws, size_t ws_size,
                              hipStream_t stream) {
  const float* x       = (const float*)d_in[0];
  const float* W_embed = (const float*)d_in[1];
  const float* b_embed = (const float*)d_in[2];
  const float* g1      = (const float*)d_in[3];
  const float* beta1   = (const float*)d_in[4];
  const float* Lre     = (const float*)d_in[5];
  const float* Lim     = (const float*)d_in[6];
  const float* Bre     = (const float*)d_in[7];
  const float* Bim     = (const float*)d_in[8];
  const float* Cre     = (const float*)d_in[9];
  const float* Cim     = (const float*)d_in[10];
  const float* Dv      = (const float*)d_in[11];
  const float* lstep   = (const float*)d_in[12];
  const float* g2      = (const float*)d_in[13];
  const float* beta2   = (const float*)d_in[14];
  const float* W_enc   = (const float*)d_in[15];
  const float* W_dec   = (const float*)d_in[16];
  const float* g3      = (const float*)d_in[17];
  const float* beta3   = (const float*)d_in[18];
  const float* W_out   = (const float*)d_in[19];
  const float* b_out   = (const float*)d_in[20];
  float* y = (float*)d_out;

  short* wimg = (short*)d_ws;                          // 176 KB frag images
  float* bu0 = (float*)((char*)d_ws + 176 * 1024);     // 256 B

  k0_prep<<<dim3(45), dim3(256), 0, stream>>>(W_embed, g1, beta1, Lre, Lim,
                                              Bre, Bim, Cre, Cim, lstep,
                                              W_enc, W_dec, W_out, wimg, bu0);
  k1_fused<<<dim3(480), dim3(320), 0, stream>>>(x, wimg, bu0, Lre, Lim, lstep,
                                                g1, beta1, b_embed, Dv, g2,
                                                beta2, g3, beta3, b_out, y);
}